// Round 15
// baseline (328.587 us; speedup 1.0000x reference)
//
#include <hip/hip_runtime.h>

#define NT 8192      // tokens
#define CD 512       // C_K = C_V = 512
#define NH 8         // heads
#define SC_N 8192

using f32x4  = __attribute__((ext_vector_type(4))) float;
using bf16x8 = __attribute__((ext_vector_type(8))) __bf16;

__device__ __forceinline__ unsigned short f2bf(float x) {
    union { float f; unsigned u; } c; c.f = x;
    unsigned r = c.u + 0x7fffu + ((c.u >> 16) & 1u);
    return (unsigned short)(r >> 16);
}
__device__ __forceinline__ float bf2f(unsigned short b) {
    union { float f; unsigned u; } c; c.u = ((unsigned)b) << 16;
    return c.f;
}

// ---------------- merged prep: input cvt (blocks 0..4095) + W transpose (4096..7167) ----------------
__global__ void prep_k(const float4* __restrict__ in, unsigned short* __restrict__ out,
                       const float* __restrict__ Wk, const float* __restrict__ Wq,
                       const float* __restrict__ Wv, const float* __restrict__ bk,
                       const float* __restrict__ bq, const float* __restrict__ bv,
                       unsigned short* __restrict__ Wt, float* __restrict__ biaskqv,
                       int* __restrict__ cnt) {
    int b = blockIdx.x;
    if (b == 0 && threadIdx.x == 0) *cnt = 0;   // reset Mt-ready counter each call
    if (b < 4096) {
        int i = b * 256 + threadIdx.x;
        float4 v = in[i];
        out[i*4+0] = f2bf(v.x);
        out[i*4+1] = f2bf(v.y);
        out[i*4+2] = f2bf(v.z);
        out[i*4+3] = f2bf(v.w);
    } else {
        int idx = (b - 4096) * 256 + threadIdx.x;   // 1536*512
        int c = idx >> 9, k = idx & 511;
        int sec = c >> 9, cc = c & 511;
        const float* W = (sec == 0) ? Wk : ((sec == 1) ? Wq : Wv);
        Wt[idx] = f2bf(W[k * 512 + cc]);
        if (idx < 1536) {
            const float* bb = (idx < 512) ? bk : ((idx < 1024) ? bq : bv);
            biaskqv[idx] = bb[idx & 511];
        }
    }
}

// ---------------- KQV GEMM with fused epilogues ----------------
__global__ __launch_bounds__(256) void kqv_gemm_k(
    const unsigned short* __restrict__ A, const unsigned short* __restrict__ Bt,
    const float* __restrict__ bias,
    unsigned short* __restrict__ kbf, unsigned short* __restrict__ qsm,
    unsigned short* __restrict__ vbf,
    float* __restrict__ pmax, float* __restrict__ psum)
{
    __shared__ unsigned short sA[128 * 32];
    __shared__ unsigned short sB[128 * 32];
    const int tid  = threadIdx.x;
    const int wid  = tid >> 6;
    const int lane = tid & 63;
    const int col0 = blockIdx.x * 128;     // 0..1535
    const int row0 = blockIdx.y * 128;
    const int by   = blockIdx.y;
    const int wr = (wid >> 1) * 64;
    const int wc = (wid & 1) * 64;
    const int fr = lane & 15;
    const int fq = lane >> 4;
    const int srow = lane >> 2;
    const int scol = (lane & 3) * 8;

    f32x4 acc[4][4] = {};

    for (int kt = 0; kt < 16; ++kt) {
        const int k0 = kt << 5;
        __syncthreads();
        #pragma unroll
        for (int s = 0; s < 2; ++s) {
            const int seg = wid * 2 + s;
            const unsigned short* gA = A + (size_t)(row0 + seg * 16 + srow) * 512 + k0 + scol;
            __builtin_amdgcn_global_load_lds(
                (const __attribute__((address_space(1))) void*)gA,
                (__attribute__((address_space(3))) void*)(sA + seg * 512), 16, 0, 0);
            const unsigned short* gB = Bt + (size_t)(col0 + seg * 16 + srow) * 512 + k0 + scol;
            __builtin_amdgcn_global_load_lds(
                (const __attribute__((address_space(1))) void*)gB,
                (__attribute__((address_space(3))) void*)(sB + seg * 512), 16, 0, 0);
        }
        __syncthreads();

        bf16x8 av[4], bfrag[4];
        #pragma unroll
        for (int m = 0; m < 4; ++m)
            av[m] = *(const bf16x8*)(sA + (wr + m * 16 + fr) * 32 + fq * 8);
        #pragma unroll
        for (int n = 0; n < 4; ++n)
            bfrag[n] = *(const bf16x8*)(sB + (wc + n * 16 + fr) * 32 + fq * 8);
        #pragma unroll
        for (int m = 0; m < 4; ++m)
            #pragma unroll
            for (int n = 0; n < 4; ++n)
                acc[m][n] = __builtin_amdgcn_mfma_f32_16x16x32_bf16(av[m], bfrag[n], acc[m][n], 0, 0, 0);
    }

    const int sec = col0 >> 9;
    const int cs0 = (col0 & 511) + wc;

    if (sec == 0) {
        const int pb = by * 2 + (wr >> 6);      // 128 partial rows
        #pragma unroll
        for (int n = 0; n < 4; ++n) {
            const int col = cs0 + n * 16 + fr;
            const float bv = bias[col];
            float vv[4][4], mx = -1e30f;
            #pragma unroll
            for (int m = 0; m < 4; ++m)
                #pragma unroll
                for (int r = 0; r < 4; ++r) {
                    float x = bf2f(f2bf(acc[m][n][r] + bv));
                    vv[m][r] = x; mx = fmaxf(mx, x);
                }
            mx = fmaxf(mx, __shfl_xor(mx, 16));
            mx = fmaxf(mx, __shfl_xor(mx, 32));
            float s = 0.f;
            #pragma unroll
            for (int m = 0; m < 4; ++m)
                #pragma unroll
                for (int r = 0; r < 4; ++r) {
                    s += __expf(vv[m][r] - mx);
                    kbf[(size_t)(row0 + wr + m * 16 + fq * 4 + r) * 512 + col] = f2bf(vv[m][r]);
                }
            s += __shfl_xor(s, 16);
            s += __shfl_xor(s, 32);
            if (lane < 16) { pmax[pb * 512 + col] = mx; psum[pb * 512 + col] = s; }
        }
    } else if (sec == 1) {
        #pragma unroll
        for (int m = 0; m < 4; ++m)
            #pragma unroll
            for (int r = 0; r < 4; ++r) {
                float e[4], mx = -1e30f;
                #pragma unroll
                for (int n = 0; n < 4; ++n) {
                    float x = bf2f(f2bf(acc[m][n][r] + bias[512 + cs0 + n * 16 + fr]));
                    e[n] = x; mx = fmaxf(mx, x);
                }
                mx = fmaxf(mx, __shfl_xor(mx, 1));
                mx = fmaxf(mx, __shfl_xor(mx, 2));
                mx = fmaxf(mx, __shfl_xor(mx, 4));
                mx = fmaxf(mx, __shfl_xor(mx, 8));
                float s = 0.f;
                #pragma unroll
                for (int n = 0; n < 4; ++n) { e[n] = __expf(e[n] - mx); s += e[n]; }
                s += __shfl_xor(s, 1);
                s += __shfl_xor(s, 2);
                s += __shfl_xor(s, 4);
                s += __shfl_xor(s, 8);
                const float rs = 1.f / s;
                const int row = row0 + wr + m * 16 + fq * 4 + r;
                #pragma unroll
                for (int n = 0; n < 4; ++n)
                    qsm[(size_t)row * 512 + cs0 + n * 16 + fr] = f2bf(e[n] * rs);
            }
    } else {
        #pragma unroll
        for (int n = 0; n < 4; ++n) {
            const int col = cs0 + n * 16 + fr;
            const float bv = bias[1024 + col];
            #pragma unroll
            for (int m = 0; m < 4; ++m)
                #pragma unroll
                for (int r = 0; r < 4; ++r)
                    vbf[(size_t)(row0 + wr + m * 16 + fq * 4 + r) * 512 + col] = f2bf(acc[m][n][r] + bv);
        }
    }
}

// ---------------- ksmctx: colms_final + ksm + context_partial fused ----------------
__global__ __launch_bounds__(256) void ksmctx_k(
    const unsigned short* __restrict__ kbf, const unsigned short* __restrict__ vbf,
    const float* __restrict__ pmax, const float* __restrict__ psum,
    unsigned short* __restrict__ ksm, float* __restrict__ pctx)
{
    const int ch = blockIdx.x;   // 32 chunks x 256 tokens
    const int h  = blockIdx.y;   // 8 heads
    const int tid = threadIdx.x, w = tid >> 6, lane = tid & 63;
    const int fr = lane & 15, fq = lane >> 4;
    __shared__ unsigned short tr[4][2][4096];   // 64 KiB; reused as fp32 scratch
    __shared__ float redm[4][64], reds[4][64], cmx[64], crc[64];

    // step A: column softmax stats for cols h*64 + (0..63)
    {
        const int c = tid & 63, q = tid >> 6;
        const int col = h * 64 + c;
        float m = -1e30f;
        for (int r = 0; r < 32; ++r) m = fmaxf(m, pmax[(q * 32 + r) * 512 + col]);
        float s = 0.f;
        for (int r = 0; r < 32; ++r)
            s += psum[(q * 32 + r) * 512 + col] * __expf(pmax[(q * 32 + r) * 512 + col] - m);
        redm[q][c] = m; reds[q][c] = s;
    }
    __syncthreads();
    if (tid < 64) {
        float m = fmaxf(fmaxf(redm[0][tid], redm[1][tid]), fmaxf(redm[2][tid], redm[3][tid]));
        float s = 0.f;
        #pragma unroll
        for (int q = 0; q < 4; ++q) s += reds[q][tid] * __expf(redm[q][tid] - m);
        cmx[tid] = m; crc[tid] = 1.f / s;
    }
    __syncthreads();

    // step B: ksm compute + transposed LDS staging + coalesced ksm write
    char* kt = (char*)&tr[w][0][0];
    char* vt = (char*)&tr[w][1][0];
    const int nbase = ch * 256 + w * 64;
    #pragma unroll
    for (int j = 0; j < 8; ++j) {
        bf16x8 kv = *(const bf16x8*)(kbf + (size_t)(nbase + lane) * 512 + h * 64 + j * 8);
        bf16x8 vv = *(const bf16x8*)(vbf + (size_t)(nbase + lane) * 512 + h * 64 + j * 8);
        unsigned short ko[8];
        #pragma unroll
        for (int e = 0; e < 8; ++e) {
            int k = j * 8 + e;
            float x = __expf(bf2f(((const unsigned short*)&kv)[e]) - cmx[k]) * crc[k];
            unsigned short us = f2bf(x);
            ko[e] = us;
            int byte = (k * 128 + lane * 2) ^ (e << 4);   // k&7 == e
            *(unsigned short*)(kt + byte) = us;
            *(unsigned short*)(vt + byte) = ((const unsigned short*)&vv)[e];
        }
        *(uint4*)(ksm + (size_t)(nbase + lane) * 512 + h * 64 + j * 8) = *(const uint4*)ko;
    }
    asm volatile("s_waitcnt lgkmcnt(0)" ::: "memory");
    __builtin_amdgcn_sched_barrier(0);

    f32x4 acc[4][4] = {};
    #pragma unroll
    for (int ks = 0; ks < 2; ++ks) {
        bf16x8 a[4], b[4];
        #pragma unroll
        for (int mf = 0; mf < 4; ++mf) {
            int row  = mf * 16 + fr;
            int byte = (row * 128 + (ks * 4 + fq) * 16) ^ ((row & 7) << 4);
            a[mf] = *(const bf16x8*)(kt + byte);
            b[mf] = *(const bf16x8*)(vt + byte);
        }
        #pragma unroll
        for (int mf = 0; mf < 4; ++mf)
            #pragma unroll
            for (int nf = 0; nf < 4; ++nf)
                acc[mf][nf] = __builtin_amdgcn_mfma_f32_16x16x32_bf16(a[mf], b[nf], acc[mf][nf], 0, 0, 0);
    }

    // cross-wave reduce through LDS (reuse tr), swizzled
    float* red = (float*)&tr[w][0][0];   // 4096 floats
    #pragma unroll
    for (int mf = 0; mf < 4; ++mf)
        #pragma unroll
        for (int nf = 0; nf < 4; ++nf)
            #pragma unroll
            for (int r = 0; r < 4; ++r) {
                int lr = mf * 16 + fq * 4 + r;
                int lc = (nf * 16 + fr) ^ (((lr >> 2) & 1) << 4);
                red[lr * 64 + lc] = acc[mf][nf][r];
            }
    __syncthreads();
    const float* rbase = (const float*)&tr[0][0][0];
    float* out = pctx + (size_t)(ch * 8 + h) * 4096;
    #pragma unroll
    for (int it = 0; it < 16; ++it) {
        int e = it * 256 + tid;
        int lr = e >> 6;
        int ph = (lr * 64) + ((e & 63) ^ (((lr >> 2) & 1) << 4));
        float s = rbase[ph] + rbase[4096 + ph] + rbase[8192 + ph] + rbase[12288 + ph];
        out[e] = s;
    }
}

// ---------------- scores + attention + mtred merged kernel ----------------
// blocks 0..1023: mtred role (ctx reduce + Mt = (ctx@Wr)^T), then release cnt.
// blocks 1024..1279: attention (spin on cnt==1024, acquire, then R12 GEMM path).
// blocks 1280..5375: scores (R12 128x128 dbuf prefetch, XCD swizzle; 1280%8==0).
// Deadlock-free: spinners (256) < co-resident capacity (~768); mtred blocks
// always dispatchable -> cnt reaches 1024. Output independent of timing.
__global__ __launch_bounds__(256, 3) void scores_attn_k(
    const unsigned short* __restrict__ qsm, const unsigned short* __restrict__ ksm,
    const float* __restrict__ pctx, const float* __restrict__ Wr,
    unsigned short* __restrict__ Mt, const float* __restrict__ br,
    float* __restrict__ attn_out, float* __restrict__ scores_out,
    int* __restrict__ cnt)
{
    __shared__ unsigned short sA0[128 * 32], sA1[128 * 32];
    __shared__ unsigned short sB0[128 * 32], sB1[128 * 32];
    const int tid  = threadIdx.x;

    // ---- mtred role ----
    if (blockIdx.x < 1024) {
        float* cr = (float*)sA0;   // 64 floats of scratch
        const int b = blockIdx.x;
        const int hk = b >> 1;
        const int o  = (b & 1) * 256 + tid;
        const int h = hk >> 6, k = hk & 63;
        if (tid < 64) {
            float s = 0.f;
            for (int p = 0; p < 32; ++p)
                s += pctx[(size_t)(p * 8 + h) * 4096 + k * 64 + tid];
            cr[tid] = s;
        }
        __syncthreads();
        const float* wp = Wr + (size_t)(h * 64) * 512 + o;
        float s = 0.f;
        #pragma unroll
        for (int j = 0; j < 64; ++j)
            s += cr[j] * wp[(size_t)j * 512];
        Mt[(size_t)o * 512 + hk] = f2bf(s);
        __threadfence();                       // release Mt
        __syncthreads();
        if (tid == 0) atomicAdd(cnt, 1);
        return;
    }

    const int wid  = tid >> 6;
    const int lane = tid & 63;
    const int wr = (wid >> 1) * 64;
    const int wc = (wid & 1) * 64;
    const int fr = lane & 15;
    const int fq = lane >> 4;
    const int srow = lane >> 2;
    const int scol = (lane & 3) * 8;

    const bool is_attn = blockIdx.x < 1280;
    int row0, col0;
    const unsigned short* Bt;
    if (is_attn) {
        if (tid == 0) { while (atomicAdd(cnt, 0) < 1024) __builtin_amdgcn_s_sleep(8); }
        __syncthreads();
        __threadfence();                       // acquire Mt
        const int bx = blockIdx.x - 1024;      // 0..255
        col0 = (bx & 3) * 128;
        row0 = (bx >> 2) * 128;
        Bt = Mt;
    } else {
        int g = blockIdx.x - 1280;             // 0..4095
        g = (g & 7) * 512 + (g >> 3);          // bijective XCD swizzle (R7-verified)
        row0 = ((g & 7) + ((g >> 9) << 3)) * 128;
        col0 = ((g >> 3) & 63) * 128;
        Bt = ksm;
    }

    f32x4 acc[4][4] = {};

    auto STAGE = [&](int kt, unsigned short* dA, unsigned short* dB) {
        const int k0 = kt << 5;
        #pragma unroll
        for (int s = 0; s < 2; ++s) {
            const int seg = wid * 2 + s;
            const unsigned short* gA = qsm + (size_t)(row0 + seg * 16 + srow) * 512 + k0 + scol;
            __builtin_amdgcn_global_load_lds(
                (const __attribute__((address_space(1))) void*)gA,
                (__attribute__((address_space(3))) void*)(dA + seg * 512), 16, 0, 0);
            const unsigned short* gB = Bt + (size_t)(col0 + seg * 16 + srow) * 512 + k0 + scol;
            __builtin_amdgcn_global_load_lds(
                (const __attribute__((address_space(1))) void*)gB,
                (__attribute__((address_space(3))) void*)(dB + seg * 512), 16, 0, 0);
        }
    };

    auto BODY = [&](int kt, const unsigned short* cA, const unsigned short* cB,
                    unsigned short* nA, unsigned short* nB) {
        if (kt < 15) STAGE(kt + 1, nA, nB);       // loads fly during this tile's MFMA
        __builtin_amdgcn_sched_barrier(0);
        bf16x8 av[4], bfrag[4];
        #pragma unroll
        for (int m = 0; m < 4; ++m)
            av[m] = *(const bf16x8*)(cA + (wr + m * 16 + fr) * 32 + fq * 8);
        #pragma unroll
        for (int n = 0; n < 4; ++n)
            bfrag[n] = *(const bf16x8*)(cB + (wc + n * 16 + fr) * 32 + fq * 8);
        __builtin_amdgcn_s_setprio(1);
        #pragma unroll
        for (int m = 0; m < 4; ++m)
            #pragma unroll
            for (int n = 0; n < 4; ++n)
                acc[m][n] = __builtin_amdgcn_mfma_f32_16x16x32_bf16(av[m], bfrag[n], acc[m][n], 0, 0, 0);
        __builtin_amdgcn_s_setprio(0);
        asm volatile("s_waitcnt vmcnt(0)" ::: "memory");   // next tile resident
        __builtin_amdgcn_s_barrier();                      // readers done, buffer reusable
        __builtin_amdgcn_sched_barrier(0);
    };

    STAGE(0, sA0, sB0);
    asm volatile("s_waitcnt vmcnt(0)" ::: "memory");
    __builtin_amdgcn_s_barrier();
    __builtin_amdgcn_sched_barrier(0);

    #pragma unroll
    for (int kt = 0; kt < 16; kt += 2) {
        BODY(kt,     sA0, sB0, sA1, sB1);
        BODY(kt + 1, sA1, sB1, sA0, sB0);
    }

    if (is_attn) {
        #pragma unroll
        for (int n = 0; n < 4; ++n) {
            const int col = col0 + wc + n * 16 + fr;
            const float bval = br[col];
            #pragma unroll
            for (int m = 0; m < 4; ++m) {
                #pragma unroll
                for (int r = 0; r < 4; ++r) {
                    const int row = row0 + wr + m * 16 + fq * 4 + r;
                    __builtin_nontemporal_store(acc[m][n][r] + bval, &attn_out[(size_t)row * 512 + col]);
                }
            }
        }
    } else {
        #pragma unroll
        for (int n = 0; n < 4; ++n) {
            const int col = col0 + wc + n * 16 + fr;
            #pragma unroll
            for (int m = 0; m < 4; ++m) {
                #pragma unroll
                for (int r = 0; r < 4; ++r) {
                    const int row = row0 + wr + m * 16 + fq * 4 + r;
                    __builtin_nontemporal_store(acc[m][n][r] * 0.125f, &scores_out[(size_t)row * SC_N + col]);
                }
            }
        }
    }
}

// ---------------- launch ----------------
extern "C" void kernel_launch(void* const* d_in, const int* in_sizes, int n_in,
                              void* d_out, int out_size, void* d_ws, size_t ws_size,
                              hipStream_t stream) {
    const float* input = (const float*)d_in[0];
    const float* Wk = (const float*)d_in[1];
    const float* bk = (const float*)d_in[2];
    const float* Wq = (const float*)d_in[3];
    const float* bq = (const float*)d_in[4];
    const float* Wv = (const float*)d_in[5];
    const float* bv = (const float*)d_in[6];
    const float* Wr = (const float*)d_in[7];
    const float* br = (const float*)d_in[8];

    char* ws = (char*)d_ws;
    unsigned short* inp_bf = (unsigned short*)ws;  ws += (size_t)NT * CD * 2;
    unsigned short* Wt     = (unsigned short*)ws;  ws += (size_t)1536 * 512 * 2;
    float* biaskqv         = (float*)ws;           ws += 1536 * 4;
    unsigned short* kbf    = (unsigned short*)ws;  ws += (size_t)NT * CD * 2;
    unsigned short* qsm    = (unsigned short*)ws;  ws += (size_t)NT * CD * 2;
    unsigned short* vbf    = (unsigned short*)ws;  ws += (size_t)NT * CD * 2;
    unsigned short* ksm    = (unsigned short*)ws;  ws += (size_t)NT * CD * 2;
    float* pmax            = (float*)ws;           ws += 128 * 512 * 4;
    float* psum            = (float*)ws;           ws += 128 * 512 * 4;
    float* pctx            = (float*)ws;           ws += (size_t)32 * 8 * 4096 * 4;
    unsigned short* Mt     = (unsigned short*)ws;  ws += (size_t)512 * 512 * 2;
    int* cnt               = (int*)ws;             ws += 128;

    float* attn_out   = (float*)d_out;
    float* scores_out = (float*)d_out + (size_t)NT * CD;

    prep_k<<<7168, 256, 0, stream>>>((const float4*)input, inp_bf,
                                     Wk, Wq, Wv, bk, bq, bv, Wt, biaskqv, cnt);

    kqv_gemm_k<<<dim3(12, 64), 256, 0, stream>>>(inp_bf, Wt, biaskqv,
                                                 kbf, qsm, vbf, pmax, psum);

    ksmctx_k<<<dim3(32, 8), 256, 0, stream>>>(kbf, vbf, pmax, psum, ksm, pctx);

    scores_attn_k<<<5376, 256, 0, stream>>>(qsm, ksm, pctx, Wr, Mt, br,
                                            attn_out, scores_out, cnt);
}

// Round 16
// 168.173 us; speedup vs baseline: 1.9539x; 1.9539x over previous
//
#include <hip/hip_runtime.h>

#define NT 8192      // tokens
#define CD 512       // C_K = C_V = 512
#define NH 8         // heads
#define SC_N 8192

using f32x4  = __attribute__((ext_vector_type(4))) float;
using bf16x8 = __attribute__((ext_vector_type(8))) __bf16;

__device__ __forceinline__ unsigned short f2bf(float x) {
    union { float f; unsigned u; } c; c.f = x;
    unsigned r = c.u + 0x7fffu + ((c.u >> 16) & 1u);
    return (unsigned short)(r >> 16);
}
__device__ __forceinline__ float bf2f(unsigned short b) {
    union { float f; unsigned u; } c; c.u = ((unsigned)b) << 16;
    return c.f;
}

// ---------------- merged prep: input cvt (blocks 0..4095) + W transpose (4096..7167) ----------------
__global__ void prep_k(const float4* __restrict__ in, unsigned short* __restrict__ out,
                       const float* __restrict__ Wk, const float* __restrict__ Wq,
                       const float* __restrict__ Wv, const float* __restrict__ bk,
                       const float* __restrict__ bq, const float* __restrict__ bv,
                       unsigned short* __restrict__ Wt, float* __restrict__ biaskqv) {
    int b = blockIdx.x;
    if (b < 4096) {
        int i = b * 256 + threadIdx.x;
        float4 v = in[i];
        out[i*4+0] = f2bf(v.x);
        out[i*4+1] = f2bf(v.y);
        out[i*4+2] = f2bf(v.z);
        out[i*4+3] = f2bf(v.w);
    } else {
        int idx = (b - 4096) * 256 + threadIdx.x;   // 1536*512
        int c = idx >> 9, k = idx & 511;
        int sec = c >> 9, cc = c & 511;
        const float* W = (sec == 0) ? Wk : ((sec == 1) ? Wq : Wv);
        Wt[idx] = f2bf(W[k * 512 + cc]);
        if (idx < 1536) {
            const float* bb = (idx < 512) ? bk : ((idx < 1024) ? bq : bv);
            biaskqv[idx] = bb[idx & 511];
        }
    }
}

// ---------------- KQV GEMM with fused epilogues ----------------
__global__ __launch_bounds__(256) void kqv_gemm_k(
    const unsigned short* __restrict__ A, const unsigned short* __restrict__ Bt,
    const float* __restrict__ bias,
    unsigned short* __restrict__ kbf, unsigned short* __restrict__ qsm,
    unsigned short* __restrict__ vbf,
    float* __restrict__ pmax, float* __restrict__ psum)
{
    __shared__ unsigned short sA[128 * 32];
    __shared__ unsigned short sB[128 * 32];
    const int tid  = threadIdx.x;
    const int wid  = tid >> 6;
    const int lane = tid & 63;
    const int col0 = blockIdx.x * 128;     // 0..1535
    const int row0 = blockIdx.y * 128;
    const int by   = blockIdx.y;
    const int wr = (wid >> 1) * 64;
    const int wc = (wid & 1) * 64;
    const int fr = lane & 15;
    const int fq = lane >> 4;
    const int srow = lane >> 2;
    const int scol = (lane & 3) * 8;

    f32x4 acc[4][4] = {};

    for (int kt = 0; kt < 16; ++kt) {
        const int k0 = kt << 5;
        __syncthreads();
        #pragma unroll
        for (int s = 0; s < 2; ++s) {
            const int seg = wid * 2 + s;
            const unsigned short* gA = A + (size_t)(row0 + seg * 16 + srow) * 512 + k0 + scol;
            __builtin_amdgcn_global_load_lds(
                (const __attribute__((address_space(1))) void*)gA,
                (__attribute__((address_space(3))) void*)(sA + seg * 512), 16, 0, 0);
            const unsigned short* gB = Bt + (size_t)(col0 + seg * 16 + srow) * 512 + k0 + scol;
            __builtin_amdgcn_global_load_lds(
                (const __attribute__((address_space(1))) void*)gB,
                (__attribute__((address_space(3))) void*)(sB + seg * 512), 16, 0, 0);
        }
        __syncthreads();

        bf16x8 av[4], bfrag[4];
        #pragma unroll
        for (int m = 0; m < 4; ++m)
            av[m] = *(const bf16x8*)(sA + (wr + m * 16 + fr) * 32 + fq * 8);
        #pragma unroll
        for (int n = 0; n < 4; ++n)
            bfrag[n] = *(const bf16x8*)(sB + (wc + n * 16 + fr) * 32 + fq * 8);
        #pragma unroll
        for (int m = 0; m < 4; ++m)
            #pragma unroll
            for (int n = 0; n < 4; ++n)
                acc[m][n] = __builtin_amdgcn_mfma_f32_16x16x32_bf16(av[m], bfrag[n], acc[m][n], 0, 0, 0);
    }

    const int sec = col0 >> 9;
    const int cs0 = (col0 & 511) + wc;

    if (sec == 0) {
        const int pb = by * 2 + (wr >> 6);      // 128 partial rows
        #pragma unroll
        for (int n = 0; n < 4; ++n) {
            const int col = cs0 + n * 16 + fr;
            const float bv = bias[col];
            float vv[4][4], mx = -1e30f;
            #pragma unroll
            for (int m = 0; m < 4; ++m)
                #pragma unroll
                for (int r = 0; r < 4; ++r) {
                    float x = bf2f(f2bf(acc[m][n][r] + bv));
                    vv[m][r] = x; mx = fmaxf(mx, x);
                }
            mx = fmaxf(mx, __shfl_xor(mx, 16));
            mx = fmaxf(mx, __shfl_xor(mx, 32));
            float s = 0.f;
            #pragma unroll
            for (int m = 0; m < 4; ++m)
                #pragma unroll
                for (int r = 0; r < 4; ++r) {
                    s += __expf(vv[m][r] - mx);
                    kbf[(size_t)(row0 + wr + m * 16 + fq * 4 + r) * 512 + col] = f2bf(vv[m][r]);
                }
            s += __shfl_xor(s, 16);
            s += __shfl_xor(s, 32);
            if (lane < 16) { pmax[pb * 512 + col] = mx; psum[pb * 512 + col] = s; }
        }
    } else if (sec == 1) {
        #pragma unroll
        for (int m = 0; m < 4; ++m)
            #pragma unroll
            for (int r = 0; r < 4; ++r) {
                float e[4], mx = -1e30f;
                #pragma unroll
                for (int n = 0; n < 4; ++n) {
                    float x = bf2f(f2bf(acc[m][n][r] + bias[512 + cs0 + n * 16 + fr]));
                    e[n] = x; mx = fmaxf(mx, x);
                }
                mx = fmaxf(mx, __shfl_xor(mx, 1));
                mx = fmaxf(mx, __shfl_xor(mx, 2));
                mx = fmaxf(mx, __shfl_xor(mx, 4));
                mx = fmaxf(mx, __shfl_xor(mx, 8));
                float s = 0.f;
                #pragma unroll
                for (int n = 0; n < 4; ++n) { e[n] = __expf(e[n] - mx); s += e[n]; }
                s += __shfl_xor(s, 1);
                s += __shfl_xor(s, 2);
                s += __shfl_xor(s, 4);
                s += __shfl_xor(s, 8);
                const float rs = 1.f / s;
                const int row = row0 + wr + m * 16 + fq * 4 + r;
                #pragma unroll
                for (int n = 0; n < 4; ++n)
                    qsm[(size_t)row * 512 + cs0 + n * 16 + fr] = f2bf(e[n] * rs);
            }
    } else {
        #pragma unroll
        for (int n = 0; n < 4; ++n) {
            const int col = cs0 + n * 16 + fr;
            const float bv = bias[1024 + col];
            #pragma unroll
            for (int m = 0; m < 4; ++m)
                #pragma unroll
                for (int r = 0; r < 4; ++r)
                    vbf[(size_t)(row0 + wr + m * 16 + fq * 4 + r) * 512 + col] = f2bf(acc[m][n][r] + bv);
        }
    }
}

// ---------------- ksmctx: colms_final + ksm + context_partial fused ----------------
__global__ __launch_bounds__(256) void ksmctx_k(
    const unsigned short* __restrict__ kbf, const unsigned short* __restrict__ vbf,
    const float* __restrict__ pmax, const float* __restrict__ psum,
    unsigned short* __restrict__ ksm, float* __restrict__ pctx)
{
    const int ch = blockIdx.x;   // 32 chunks x 256 tokens
    const int h  = blockIdx.y;   // 8 heads
    const int tid = threadIdx.x, w = tid >> 6, lane = tid & 63;
    const int fr = lane & 15, fq = lane >> 4;
    __shared__ unsigned short tr[4][2][4096];   // 64 KiB; reused as fp32 scratch
    __shared__ float redm[4][64], reds[4][64], cmx[64], crc[64];

    // step A: column softmax stats for cols h*64 + (0..63)
    {
        const int c = tid & 63, q = tid >> 6;
        const int col = h * 64 + c;
        float m = -1e30f;
        for (int r = 0; r < 32; ++r) m = fmaxf(m, pmax[(q * 32 + r) * 512 + col]);
        float s = 0.f;
        for (int r = 0; r < 32; ++r)
            s += psum[(q * 32 + r) * 512 + col] * __expf(pmax[(q * 32 + r) * 512 + col] - m);
        redm[q][c] = m; reds[q][c] = s;
    }
    __syncthreads();
    if (tid < 64) {
        float m = fmaxf(fmaxf(redm[0][tid], redm[1][tid]), fmaxf(redm[2][tid], redm[3][tid]));
        float s = 0.f;
        #pragma unroll
        for (int q = 0; q < 4; ++q) s += reds[q][tid] * __expf(redm[q][tid] - m);
        cmx[tid] = m; crc[tid] = 1.f / s;
    }
    __syncthreads();

    // step B: ksm compute + transposed LDS staging + coalesced ksm write
    char* kt = (char*)&tr[w][0][0];
    char* vt = (char*)&tr[w][1][0];
    const int nbase = ch * 256 + w * 64;
    #pragma unroll
    for (int j = 0; j < 8; ++j) {
        bf16x8 kv = *(const bf16x8*)(kbf + (size_t)(nbase + lane) * 512 + h * 64 + j * 8);
        bf16x8 vv = *(const bf16x8*)(vbf + (size_t)(nbase + lane) * 512 + h * 64 + j * 8);
        unsigned short ko[8];
        #pragma unroll
        for (int e = 0; e < 8; ++e) {
            int k = j * 8 + e;
            float x = __expf(bf2f(((const unsigned short*)&kv)[e]) - cmx[k]) * crc[k];
            unsigned short us = f2bf(x);
            ko[e] = us;
            int byte = (k * 128 + lane * 2) ^ (e << 4);   // k&7 == e
            *(unsigned short*)(kt + byte) = us;
            *(unsigned short*)(vt + byte) = ((const unsigned short*)&vv)[e];
        }
        *(uint4*)(ksm + (size_t)(nbase + lane) * 512 + h * 64 + j * 8) = *(const uint4*)ko;
    }
    asm volatile("s_waitcnt lgkmcnt(0)" ::: "memory");
    __builtin_amdgcn_sched_barrier(0);

    f32x4 acc[4][4] = {};
    #pragma unroll
    for (int ks = 0; ks < 2; ++ks) {
        bf16x8 a[4], b[4];
        #pragma unroll
        for (int mf = 0; mf < 4; ++mf) {
            int row  = mf * 16 + fr;
            int byte = (row * 128 + (ks * 4 + fq) * 16) ^ ((row & 7) << 4);
            a[mf] = *(const bf16x8*)(kt + byte);
            b[mf] = *(const bf16x8*)(vt + byte);
        }
        #pragma unroll
        for (int mf = 0; mf < 4; ++mf)
            #pragma unroll
            for (int nf = 0; nf < 4; ++nf)
                acc[mf][nf] = __builtin_amdgcn_mfma_f32_16x16x32_bf16(a[mf], b[nf], acc[mf][nf], 0, 0, 0);
    }

    // cross-wave reduce through LDS (reuse tr), swizzled
    float* red = (float*)&tr[w][0][0];   // 4096 floats
    #pragma unroll
    for (int mf = 0; mf < 4; ++mf)
        #pragma unroll
        for (int nf = 0; nf < 4; ++nf)
            #pragma unroll
            for (int r = 0; r < 4; ++r) {
                int lr = mf * 16 + fq * 4 + r;
                int lc = (nf * 16 + fr) ^ (((lr >> 2) & 1) << 4);
                red[lr * 64 + lc] = acc[mf][nf][r];
            }
    __syncthreads();
    const float* rbase = (const float*)&tr[0][0][0];
    float* out = pctx + (size_t)(ch * 8 + h) * 4096;
    #pragma unroll
    for (int it = 0; it < 16; ++it) {
        int e = it * 256 + tid;
        int lr = e >> 6;
        int ph = (lr * 64) + ((e & 63) ^ (((lr >> 2) & 1) << 4));
        float s = rbase[ph] + rbase[4096 + ph] + rbase[8192 + ph] + rbase[12288 + ph];
        out[e] = s;
    }
}

// ---------------- mtred: context_reduce + mt fused ----------------
__global__ void mtred_k(const float* __restrict__ pctx, const float* __restrict__ Wr,
                        unsigned short* __restrict__ Mt) {
    __shared__ float cr[64];
    const int b = blockIdx.x;            // 1024
    const int hk = b >> 1;
    const int o  = (b & 1) * 256 + threadIdx.x;
    const int h = hk >> 6, k = hk & 63;
    if (threadIdx.x < 64) {
        float s = 0.f;
        for (int p = 0; p < 32; ++p)
            s += pctx[(size_t)(p * 8 + h) * 4096 + k * 64 + threadIdx.x];
        cr[threadIdx.x] = s;
    }
    __syncthreads();
    const float* wp = Wr + (size_t)(h * 64) * 512 + o;
    float s = 0.f;
    #pragma unroll
    for (int j = 0; j < 64; ++j)
        s += cr[j] * wp[(size_t)j * 512];
    Mt[(size_t)o * 512 + hk] = f2bf(s);
}

// ---------------- scores + attention merged GEMM: 128x128, double-buffered LDS ----------------
// blocks 0..255: attention = qsm @ Mt^T + br; blocks 256..4351: scores (XCD swizzle).
// Minimum-2-phase (T3 catalog recipe): STAGE(t+1) into buf^1 BEFORE reading buf,
// one vmcnt(0)+barrier per tile -> next tile's loads land during current MFMA.
// 32 KiB LDS + VGPR cap (min 3 waves/EU) -> 3 blocks/CU preserved.
__global__ __launch_bounds__(256, 3) void scores_attn_k(
    const unsigned short* __restrict__ qsm, const unsigned short* __restrict__ ksm,
    const unsigned short* __restrict__ Mt, const float* __restrict__ br,
    float* __restrict__ attn_out, float* __restrict__ scores_out)
{
    __shared__ unsigned short sA0[128 * 32], sA1[128 * 32];
    __shared__ unsigned short sB0[128 * 32], sB1[128 * 32];
    const int tid  = threadIdx.x;
    const int wid  = tid >> 6;
    const int lane = tid & 63;
    const int wr = (wid >> 1) * 64;
    const int wc = (wid & 1) * 64;
    const int fr = lane & 15;
    const int fq = lane >> 4;
    const int srow = lane >> 2;
    const int scol = (lane & 3) * 8;

    const bool is_attn = blockIdx.x < 256;
    int row0, col0;
    const unsigned short* Bt;
    if (is_attn) {
        const int bx = blockIdx.x;
        col0 = (bx & 3) * 128;
        row0 = (bx >> 2) * 128;
        Bt = Mt;
    } else {
        int g = blockIdx.x - 256;                 // 0..4095
        g = (g & 7) * 512 + (g >> 3);             // bijective XCD swizzle (R7-verified)
        row0 = ((g & 7) + ((g >> 9) << 3)) * 128;
        col0 = ((g >> 3) & 63) * 128;
        Bt = ksm;
    }

    f32x4 acc[4][4] = {};

    auto STAGE = [&](int kt, unsigned short* dA, unsigned short* dB) {
        const int k0 = kt << 5;
        #pragma unroll
        for (int s = 0; s < 2; ++s) {
            const int seg = wid * 2 + s;
            const unsigned short* gA = qsm + (size_t)(row0 + seg * 16 + srow) * 512 + k0 + scol;
            __builtin_amdgcn_global_load_lds(
                (const __attribute__((address_space(1))) void*)gA,
                (__attribute__((address_space(3))) void*)(dA + seg * 512), 16, 0, 0);
            const unsigned short* gB = Bt + (size_t)(col0 + seg * 16 + srow) * 512 + k0 + scol;
            __builtin_amdgcn_global_load_lds(
                (const __attribute__((address_space(1))) void*)gB,
                (__attribute__((address_space(3))) void*)(dB + seg * 512), 16, 0, 0);
        }
    };

    auto BODY = [&](int kt, const unsigned short* cA, const unsigned short* cB,
                    unsigned short* nA, unsigned short* nB) {
        if (kt < 15) STAGE(kt + 1, nA, nB);       // loads fly during this tile's MFMA
        __builtin_amdgcn_sched_barrier(0);        // keep stage-issue ahead of ds_reads
        bf16x8 av[4], bfrag[4];
        #pragma unroll
        for (int m = 0; m < 4; ++m)
            av[m] = *(const bf16x8*)(cA + (wr + m * 16 + fr) * 32 + fq * 8);
        #pragma unroll
        for (int n = 0; n < 4; ++n)
            bfrag[n] = *(const bf16x8*)(cB + (wc + n * 16 + fr) * 32 + fq * 8);
        __builtin_amdgcn_s_setprio(1);
        #pragma unroll
        for (int m = 0; m < 4; ++m)
            #pragma unroll
            for (int n = 0; n < 4; ++n)
                acc[m][n] = __builtin_amdgcn_mfma_f32_16x16x32_bf16(av[m], bfrag[n], acc[m][n], 0, 0, 0);
        __builtin_amdgcn_s_setprio(0);
        asm volatile("s_waitcnt vmcnt(0)" ::: "memory");   // next tile resident
        __builtin_amdgcn_s_barrier();                      // readers done, buffer reusable
        __builtin_amdgcn_sched_barrier(0);
    };

    STAGE(0, sA0, sB0);
    asm volatile("s_waitcnt vmcnt(0)" ::: "memory");
    __builtin_amdgcn_s_barrier();
    __builtin_amdgcn_sched_barrier(0);

    #pragma unroll
    for (int kt = 0; kt < 16; kt += 2) {
        BODY(kt,     sA0, sB0, sA1, sB1);
        BODY(kt + 1, sA1, sB1, sA0, sB0);
    }

    if (is_attn) {
        #pragma unroll
        for (int n = 0; n < 4; ++n) {
            const int col = col0 + wc + n * 16 + fr;
            const float bval = br[col];
            #pragma unroll
            for (int m = 0; m < 4; ++m) {
                #pragma unroll
                for (int r = 0; r < 4; ++r) {
                    const int row = row0 + wr + m * 16 + fq * 4 + r;
                    __builtin_nontemporal_store(acc[m][n][r] + bval, &attn_out[(size_t)row * 512 + col]);
                }
            }
        }
    } else {
        #pragma unroll
        for (int n = 0; n < 4; ++n) {
            const int col = col0 + wc + n * 16 + fr;
            #pragma unroll
            for (int m = 0; m < 4; ++m) {
                #pragma unroll
                for (int r = 0; r < 4; ++r) {
                    const int row = row0 + wr + m * 16 + fq * 4 + r;
                    __builtin_nontemporal_store(acc[m][n][r] * 0.125f, &scores_out[(size_t)row * SC_N + col]);
                }
            }
        }
    }
}

// ---------------- launch ----------------
extern "C" void kernel_launch(void* const* d_in, const int* in_sizes, int n_in,
                              void* d_out, int out_size, void* d_ws, size_t ws_size,
                              hipStream_t stream) {
    const float* input = (const float*)d_in[0];
    const float* Wk = (const float*)d_in[1];
    const float* bk = (const float*)d_in[2];
    const float* Wq = (const float*)d_in[3];
    const float* bq = (const float*)d_in[4];
    const float* Wv = (const float*)d_in[5];
    const float* bv = (const float*)d_in[6];
    const float* Wr = (const float*)d_in[7];
    const float* br = (const float*)d_in[8];

    char* ws = (char*)d_ws;
    unsigned short* inp_bf = (unsigned short*)ws;  ws += (size_t)NT * CD * 2;
    unsigned short* Wt     = (unsigned short*)ws;  ws += (size_t)1536 * 512 * 2;
    float* biaskqv         = (float*)ws;           ws += 1536 * 4;
    unsigned short* kbf    = (unsigned short*)ws;  ws += (size_t)NT * CD * 2;
    unsigned short* qsm    = (unsigned short*)ws;  ws += (size_t)NT * CD * 2;
    unsigned short* vbf    = (unsigned short*)ws;  ws += (size_t)NT * CD * 2;
    unsigned short* ksm    = (unsigned short*)ws;  ws += (size_t)NT * CD * 2;
    float* pmax            = (float*)ws;           ws += 128 * 512 * 4;
    float* psum            = (float*)ws;           ws += 128 * 512 * 4;
    float* pctx            = (float*)ws;           ws += (size_t)32 * 8 * 4096 * 4;
    unsigned short* Mt     = (unsigned short*)ws;  ws += (size_t)512 * 512 * 2;

    float* attn_out   = (float*)d_out;
    float* scores_out = (float*)d_out + (size_t)NT * CD;

    prep_k<<<7168, 256, 0, stream>>>((const float4*)input, inp_bf,
                                     Wk, Wq, Wv, bk, bq, bv, Wt, biaskqv);

    kqv_gemm_k<<<dim3(12, 64), 256, 0, stream>>>(inp_bf, Wt, biaskqv,
                                                 kbf, qsm, vbf, pmax, psum);

    ksmctx_k<<<dim3(32, 8), 256, 0, stream>>>(kbf, vbf, pmax, psum, ksm, pctx);

    mtred_k<<<1024, 256, 0, stream>>>(pctx, Wr, Mt);

    scores_attn_k<<<4352, 256, 0, stream>>>(qsm, ksm, Mt, br, attn_out, scores_out);
}

// Round 17
// 167.500 us; speedup vs baseline: 1.9617x; 1.0040x over previous
//
#include <hip/hip_runtime.h>

#define NT 8192      // tokens
#define CD 512       // C_K = C_V = 512
#define NH 8         // heads
#define SC_N 8192

using f32x4  = __attribute__((ext_vector_type(4))) float;
using bf16x8 = __attribute__((ext_vector_type(8))) __bf16;

__device__ __forceinline__ unsigned short f2bf(float x) {
    union { float f; unsigned u; } c; c.f = x;
    unsigned r = c.u + 0x7fffu + ((c.u >> 16) & 1u);
    return (unsigned short)(r >> 16);
}
__device__ __forceinline__ float bf2f(unsigned short b) {
    union { float f; unsigned u; } c; c.u = ((unsigned)b) << 16;
    return c.f;
}

// ---------------- merged prep: input cvt (blocks 0..4095) + W transpose (4096..7167) ----------------
__global__ void prep_k(const float4* __restrict__ in, unsigned short* __restrict__ out,
                       const float* __restrict__ Wk, const float* __restrict__ Wq,
                       const float* __restrict__ Wv, const float* __restrict__ bk,
                       const float* __restrict__ bq, const float* __restrict__ bv,
                       unsigned short* __restrict__ Wt, float* __restrict__ biaskqv) {
    int b = blockIdx.x;
    if (b < 4096) {
        int i = b * 256 + threadIdx.x;
        float4 v = in[i];
        out[i*4+0] = f2bf(v.x);
        out[i*4+1] = f2bf(v.y);
        out[i*4+2] = f2bf(v.z);
        out[i*4+3] = f2bf(v.w);
    } else {
        int idx = (b - 4096) * 256 + threadIdx.x;   // 1536*512
        int c = idx >> 9, k = idx & 511;
        int sec = c >> 9, cc = c & 511;
        const float* W = (sec == 0) ? Wk : ((sec == 1) ? Wq : Wv);
        Wt[idx] = f2bf(W[k * 512 + cc]);
        if (idx < 1536) {
            const float* bb = (idx < 512) ? bk : ((idx < 1024) ? bq : bv);
            biaskqv[idx] = bb[idx & 511];
        }
    }
}

// ---------------- KQV GEMM with fused epilogues ----------------
__global__ __launch_bounds__(256) void kqv_gemm_k(
    const unsigned short* __restrict__ A, const unsigned short* __restrict__ Bt,
    const float* __restrict__ bias,
    unsigned short* __restrict__ kbf, unsigned short* __restrict__ qsm,
    unsigned short* __restrict__ vbf,
    float* __restrict__ pmax, float* __restrict__ psum)
{
    __shared__ unsigned short sA[128 * 32];
    __shared__ unsigned short sB[128 * 32];
    const int tid  = threadIdx.x;
    const int wid  = tid >> 6;
    const int lane = tid & 63;
    const int col0 = blockIdx.x * 128;     // 0..1535
    const int row0 = blockIdx.y * 128;
    const int by   = blockIdx.y;
    const int wr = (wid >> 1) * 64;
    const int wc = (wid & 1) * 64;
    const int fr = lane & 15;
    const int fq = lane >> 4;
    const int srow = lane >> 2;
    const int scol = (lane & 3) * 8;

    f32x4 acc[4][4] = {};

    for (int kt = 0; kt < 16; ++kt) {
        const int k0 = kt << 5;
        __syncthreads();
        #pragma unroll
        for (int s = 0; s < 2; ++s) {
            const int seg = wid * 2 + s;
            const unsigned short* gA = A + (size_t)(row0 + seg * 16 + srow) * 512 + k0 + scol;
            __builtin_amdgcn_global_load_lds(
                (const __attribute__((address_space(1))) void*)gA,
                (__attribute__((address_space(3))) void*)(sA + seg * 512), 16, 0, 0);
            const unsigned short* gB = Bt + (size_t)(col0 + seg * 16 + srow) * 512 + k0 + scol;
            __builtin_amdgcn_global_load_lds(
                (const __attribute__((address_space(1))) void*)gB,
                (__attribute__((address_space(3))) void*)(sB + seg * 512), 16, 0, 0);
        }
        __syncthreads();

        bf16x8 av[4], bfrag[4];
        #pragma unroll
        for (int m = 0; m < 4; ++m)
            av[m] = *(const bf16x8*)(sA + (wr + m * 16 + fr) * 32 + fq * 8);
        #pragma unroll
        for (int n = 0; n < 4; ++n)
            bfrag[n] = *(const bf16x8*)(sB + (wc + n * 16 + fr) * 32 + fq * 8);
        #pragma unroll
        for (int m = 0; m < 4; ++m)
            #pragma unroll
            for (int n = 0; n < 4; ++n)
                acc[m][n] = __builtin_amdgcn_mfma_f32_16x16x32_bf16(av[m], bfrag[n], acc[m][n], 0, 0, 0);
    }

    const int sec = col0 >> 9;
    const int cs0 = (col0 & 511) + wc;

    if (sec == 0) {
        const int pb = by * 2 + (wr >> 6);      // 128 partial rows
        #pragma unroll
        for (int n = 0; n < 4; ++n) {
            const int col = cs0 + n * 16 + fr;
            const float bv = bias[col];
            float vv[4][4], mx = -1e30f;
            #pragma unroll
            for (int m = 0; m < 4; ++m)
                #pragma unroll
                for (int r = 0; r < 4; ++r) {
                    float x = bf2f(f2bf(acc[m][n][r] + bv));
                    vv[m][r] = x; mx = fmaxf(mx, x);
                }
            mx = fmaxf(mx, __shfl_xor(mx, 16));
            mx = fmaxf(mx, __shfl_xor(mx, 32));
            float s = 0.f;
            #pragma unroll
            for (int m = 0; m < 4; ++m)
                #pragma unroll
                for (int r = 0; r < 4; ++r) {
                    s += __expf(vv[m][r] - mx);
                    kbf[(size_t)(row0 + wr + m * 16 + fq * 4 + r) * 512 + col] = f2bf(vv[m][r]);
                }
            s += __shfl_xor(s, 16);
            s += __shfl_xor(s, 32);
            if (lane < 16) { pmax[pb * 512 + col] = mx; psum[pb * 512 + col] = s; }
        }
    } else if (sec == 1) {
        #pragma unroll
        for (int m = 0; m < 4; ++m)
            #pragma unroll
            for (int r = 0; r < 4; ++r) {
                float e[4], mx = -1e30f;
                #pragma unroll
                for (int n = 0; n < 4; ++n) {
                    float x = bf2f(f2bf(acc[m][n][r] + bias[512 + cs0 + n * 16 + fr]));
                    e[n] = x; mx = fmaxf(mx, x);
                }
                mx = fmaxf(mx, __shfl_xor(mx, 1));
                mx = fmaxf(mx, __shfl_xor(mx, 2));
                mx = fmaxf(mx, __shfl_xor(mx, 4));
                mx = fmaxf(mx, __shfl_xor(mx, 8));
                float s = 0.f;
                #pragma unroll
                for (int n = 0; n < 4; ++n) { e[n] = __expf(e[n] - mx); s += e[n]; }
                s += __shfl_xor(s, 1);
                s += __shfl_xor(s, 2);
                s += __shfl_xor(s, 4);
                s += __shfl_xor(s, 8);
                const float rs = 1.f / s;
                const int row = row0 + wr + m * 16 + fq * 4 + r;
                #pragma unroll
                for (int n = 0; n < 4; ++n)
                    qsm[(size_t)row * 512 + cs0 + n * 16 + fr] = f2bf(e[n] * rs);
            }
    } else {
        #pragma unroll
        for (int n = 0; n < 4; ++n) {
            const int col = cs0 + n * 16 + fr;
            const float bv = bias[1024 + col];
            #pragma unroll
            for (int m = 0; m < 4; ++m)
                #pragma unroll
                for (int r = 0; r < 4; ++r)
                    vbf[(size_t)(row0 + wr + m * 16 + fq * 4 + r) * 512 + col] = f2bf(acc[m][n][r] + bv);
        }
    }
}

// ---------------- ksmctx: colms_final + ksm + context_partial fused ----------------
__global__ __launch_bounds__(256) void ksmctx_k(
    const unsigned short* __restrict__ kbf, const unsigned short* __restrict__ vbf,
    const float* __restrict__ pmax, const float* __restrict__ psum,
    unsigned short* __restrict__ ksm, float* __restrict__ pctx)
{
    const int ch = blockIdx.x;   // 32 chunks x 256 tokens
    const int h  = blockIdx.y;   // 8 heads
    const int tid = threadIdx.x, w = tid >> 6, lane = tid & 63;
    const int fr = lane & 15, fq = lane >> 4;
    __shared__ unsigned short tr[4][2][4096];   // 64 KiB; reused as fp32 scratch
    __shared__ float redm[4][64], reds[4][64], cmx[64], crc[64];

    // step A: column softmax stats for cols h*64 + (0..63)
    {
        const int c = tid & 63, q = tid >> 6;
        const int col = h * 64 + c;
        float m = -1e30f;
        for (int r = 0; r < 32; ++r) m = fmaxf(m, pmax[(q * 32 + r) * 512 + col]);
        float s = 0.f;
        for (int r = 0; r < 32; ++r)
            s += psum[(q * 32 + r) * 512 + col] * __expf(pmax[(q * 32 + r) * 512 + col] - m);
        redm[q][c] = m; reds[q][c] = s;
    }
    __syncthreads();
    if (tid < 64) {
        float m = fmaxf(fmaxf(redm[0][tid], redm[1][tid]), fmaxf(redm[2][tid], redm[3][tid]));
        float s = 0.f;
        #pragma unroll
        for (int q = 0; q < 4; ++q) s += reds[q][tid] * __expf(redm[q][tid] - m);
        cmx[tid] = m; crc[tid] = 1.f / s;
    }
    __syncthreads();

    // step B: ksm compute + transposed LDS staging + coalesced ksm write
    char* kt = (char*)&tr[w][0][0];
    char* vt = (char*)&tr[w][1][0];
    const int nbase = ch * 256 + w * 64;
    #pragma unroll
    for (int j = 0; j < 8; ++j) {
        bf16x8 kv = *(const bf16x8*)(kbf + (size_t)(nbase + lane) * 512 + h * 64 + j * 8);
        bf16x8 vv = *(const bf16x8*)(vbf + (size_t)(nbase + lane) * 512 + h * 64 + j * 8);
        unsigned short ko[8];
        #pragma unroll
        for (int e = 0; e < 8; ++e) {
            int k = j * 8 + e;
            float x = __expf(bf2f(((const unsigned short*)&kv)[e]) - cmx[k]) * crc[k];
            unsigned short us = f2bf(x);
            ko[e] = us;
            int byte = (k * 128 + lane * 2) ^ (e << 4);   // k&7 == e
            *(unsigned short*)(kt + byte) = us;
            *(unsigned short*)(vt + byte) = ((const unsigned short*)&vv)[e];
        }
        *(uint4*)(ksm + (size_t)(nbase + lane) * 512 + h * 64 + j * 8) = *(const uint4*)ko;
    }
    asm volatile("s_waitcnt lgkmcnt(0)" ::: "memory");
    __builtin_amdgcn_sched_barrier(0);

    f32x4 acc[4][4] = {};
    #pragma unroll
    for (int ks = 0; ks < 2; ++ks) {
        bf16x8 a[4], b[4];
        #pragma unroll
        for (int mf = 0; mf < 4; ++mf) {
            int row  = mf * 16 + fr;
            int byte = (row * 128 + (ks * 4 + fq) * 16) ^ ((row & 7) << 4);
            a[mf] = *(const bf16x8*)(kt + byte);
            b[mf] = *(const bf16x8*)(vt + byte);
        }
        #pragma unroll
        for (int mf = 0; mf < 4; ++mf)
            #pragma unroll
            for (int nf = 0; nf < 4; ++nf)
                acc[mf][nf] = __builtin_amdgcn_mfma_f32_16x16x32_bf16(a[mf], b[nf], acc[mf][nf], 0, 0, 0);
    }

    // cross-wave reduce through LDS (reuse tr), swizzled
    float* red = (float*)&tr[w][0][0];   // 4096 floats
    #pragma unroll
    for (int mf = 0; mf < 4; ++mf)
        #pragma unroll
        for (int nf = 0; nf < 4; ++nf)
            #pragma unroll
            for (int r = 0; r < 4; ++r) {
                int lr = mf * 16 + fq * 4 + r;
                int lc = (nf * 16 + fr) ^ (((lr >> 2) & 1) << 4);
                red[lr * 64 + lc] = acc[mf][nf][r];
            }
    __syncthreads();
    const float* rbase = (const float*)&tr[0][0][0];
    float* out = pctx + (size_t)(ch * 8 + h) * 4096;
    #pragma unroll
    for (int it = 0; it < 16; ++it) {
        int e = it * 256 + tid;
        int lr = e >> 6;
        int ph = (lr * 64) + ((e & 63) ^ (((lr >> 2) & 1) << 4));
        float s = rbase[ph] + rbase[4096 + ph] + rbase[8192 + ph] + rbase[12288 + ph];
        out[e] = s;
    }
}

// ---------------- mtred: context_reduce + mt fused ----------------
__global__ void mtred_k(const float* __restrict__ pctx, const float* __restrict__ Wr,
                        unsigned short* __restrict__ Mt) {
    __shared__ float cr[64];
    const int b = blockIdx.x;            // 1024
    const int hk = b >> 1;
    const int o  = (b & 1) * 256 + threadIdx.x;
    const int h = hk >> 6, k = hk & 63;
    if (threadIdx.x < 64) {
        float s = 0.f;
        for (int p = 0; p < 32; ++p)
            s += pctx[(size_t)(p * 8 + h) * 4096 + k * 64 + threadIdx.x];
        cr[threadIdx.x] = s;
    }
    __syncthreads();
    const float* wp = Wr + (size_t)(h * 64) * 512 + o;
    float s = 0.f;
    #pragma unroll
    for (int j = 0; j < 64; ++j)
        s += cr[j] * wp[(size_t)j * 512];
    Mt[(size_t)o * 512 + hk] = f2bf(s);
}

// ---------------- scores + attention merged GEMM: 128x128 dbuf + bank-conflict swizzle ----------------
// blocks 0..255: attention = qsm @ Mt^T + br; blocks 256..4351: scores (XCD swizzle).
// R12 prefetch body + T2 swizzle (rule #21: both-sides): LDS writes stay linear
// (global_load_lds), global SOURCE unit is pre-swizzled u^s and the ds_read unit
// applies the same XOR. s(row) = (row&3)^((row>>2)&3); staging form s =
// ((lane>>2)&3)^((lane>>4)&3) (seg-independent), read form s = (fr&3)^((fr>>2)&3)
// (wr/m vanish mod 4). Result: quarter-wave ds_read_b128 banks exactly 2-way (free)
// vs 8-way before (R15 counters: 8.9M conflicts).
__global__ __launch_bounds__(256, 3) void scores_attn_k(
    const unsigned short* __restrict__ qsm, const unsigned short* __restrict__ ksm,
    const unsigned short* __restrict__ Mt, const float* __restrict__ br,
    float* __restrict__ attn_out, float* __restrict__ scores_out)
{
    __shared__ unsigned short sA0[128 * 32], sA1[128 * 32];
    __shared__ unsigned short sB0[128 * 32], sB1[128 * 32];
    const int tid  = threadIdx.x;
    const int wid  = tid >> 6;
    const int lane = tid & 63;
    const int wr = (wid >> 1) * 64;
    const int wc = (wid & 1) * 64;
    const int fr = lane & 15;
    const int fq = lane >> 4;
    const int srow = lane >> 2;
    // pre-swizzled staging source unit: u = (lane&3) ^ s(row), s seg-independent
    const int scol = (((lane & 3) ^ ((lane >> 2) & 3) ^ ((lane >> 4) & 3)) & 3) * 8;
    // read-side swizzled unit: fq ^ s(row), s = (fr&3)^((fr>>2)&3)
    const int rq = (fq ^ (fr & 3) ^ ((fr >> 2) & 3)) & 3;

    const bool is_attn = blockIdx.x < 256;
    int row0, col0;
    const unsigned short* Bt;
    if (is_attn) {
        const int bx = blockIdx.x;
        col0 = (bx & 3) * 128;
        row0 = (bx >> 2) * 128;
        Bt = Mt;
    } else {
        int g = blockIdx.x - 256;                 // 0..4095
        g = (g & 7) * 512 + (g >> 3);             // bijective XCD swizzle (R7-verified)
        row0 = ((g & 7) + ((g >> 9) << 3)) * 128;
        col0 = ((g >> 3) & 63) * 128;
        Bt = ksm;
    }

    f32x4 acc[4][4] = {};

    auto STAGE = [&](int kt, unsigned short* dA, unsigned short* dB) {
        const int k0 = kt << 5;
        #pragma unroll
        for (int s = 0; s < 2; ++s) {
            const int seg = wid * 2 + s;
            const unsigned short* gA = qsm + (size_t)(row0 + seg * 16 + srow) * 512 + k0 + scol;
            __builtin_amdgcn_global_load_lds(
                (const __attribute__((address_space(1))) void*)gA,
                (__attribute__((address_space(3))) void*)(dA + seg * 512), 16, 0, 0);
            const unsigned short* gB = Bt + (size_t)(col0 + seg * 16 + srow) * 512 + k0 + scol;
            __builtin_amdgcn_global_load_lds(
                (const __attribute__((address_space(1))) void*)gB,
                (__attribute__((address_space(3))) void*)(dB + seg * 512), 16, 0, 0);
        }
    };

    auto BODY = [&](int kt, const unsigned short* cA, const unsigned short* cB,
                    unsigned short* nA, unsigned short* nB) {
        if (kt < 15) STAGE(kt + 1, nA, nB);       // loads fly during this tile's MFMA
        __builtin_amdgcn_sched_barrier(0);        // keep stage-issue ahead of ds_reads
        bf16x8 av[4], bfrag[4];
        #pragma unroll
        for (int m = 0; m < 4; ++m)
            av[m] = *(const bf16x8*)(cA + (wr + m * 16 + fr) * 32 + rq * 8);
        #pragma unroll
        for (int n = 0; n < 4; ++n)
            bfrag[n] = *(const bf16x8*)(cB + (wc + n * 16 + fr) * 32 + rq * 8);
        __builtin_amdgcn_s_setprio(1);
        #pragma unroll
        for (int m = 0; m < 4; ++m)
            #pragma unroll
            for (int n = 0; n < 4; ++n)
                acc[m][n] = __builtin_amdgcn_mfma_f32_16x16x32_bf16(av[m], bfrag[n], acc[m][n], 0, 0, 0);
        __builtin_amdgcn_s_setprio(0);
        asm volatile("s_waitcnt vmcnt(0)" ::: "memory");   // next tile resident
        __builtin_amdgcn_s_barrier();                      // readers done, buffer reusable
        __builtin_amdgcn_sched_barrier(0);
    };

    STAGE(0, sA0, sB0);
    asm volatile("s_waitcnt vmcnt(0)" ::: "memory");
    __builtin_amdgcn_s_barrier();
    __builtin_amdgcn_sched_barrier(0);

    #pragma unroll
    for (int kt = 0; kt < 16; kt += 2) {
        BODY(kt,     sA0, sB0, sA1, sB1);
        BODY(kt + 1, sA1, sB1, sA0, sB0);
    }

    if (is_attn) {
        #pragma unroll
        for (int n = 0; n < 4; ++n) {
            const int col = col0 + wc + n * 16 + fr;
            const float bval = br[col];
            #pragma unroll
            for (int m = 0; m < 4; ++m) {
                #pragma unroll
                for (int r = 0; r < 4; ++r) {
                    const int row = row0 + wr + m * 16 + fq * 4 + r;
                    __builtin_nontemporal_store(acc[m][n][r] + bval, &attn_out[(size_t)row * 512 + col]);
                }
            }
        }
    } else {
        #pragma unroll
        for (int n = 0; n < 4; ++n) {
            const int col = col0 + wc + n * 16 + fr;
            #pragma unroll
            for (int m = 0; m < 4; ++m) {
                #pragma unroll
                for (int r = 0; r < 4; ++r) {
                    const int row = row0 + wr + m * 16 + fq * 4 + r;
                    __builtin_nontemporal_store(acc[m][n][r] * 0.125f, &scores_out[(size_t)row * SC_N + col]);
                }
            }
        }
    }
}

// ---------------- launch ----------------
extern "C" void kernel_launch(void* const* d_in, const int* in_sizes, int n_in,
                              void* d_out, int out_size, void* d_ws, size_t ws_size,
                              hipStream_t stream) {
    const float* input = (const float*)d_in[0];
    const float* Wk = (const float*)d_in[1];
    const float* bk = (const float*)d_in[2];
    const float* Wq = (const float*)d_in[3];
    const float* bq = (const float*)d_in[4];
    const float* Wv = (const float*)d_in[5];
    const float* bv = (const float*)d_in[6];
    const float* Wr = (const float*)d_in[7];
    const float* br = (const float*)d_in[8];

    char* ws = (char*)d_ws;
    unsigned short* inp_bf = (unsigned short*)ws;  ws += (size_t)NT * CD * 2;
    unsigned short* Wt     = (unsigned short*)ws;  ws += (size_t)1536 * 512 * 2;
    float* biaskqv         = (float*)ws;           ws += 1536 * 4;
    unsigned short* kbf    = (unsigned short*)ws;  ws += (size_t)NT * CD * 2;
    unsigned short* qsm    = (unsigned short*)ws;  ws += (size_t)NT * CD * 2;
    unsigned short* vbf    = (unsigned short*)ws;  ws += (size_t)NT * CD * 2;
    unsigned short* ksm    = (unsigned short*)ws;  ws += (size_t)NT * CD * 2;
    float* pmax            = (float*)ws;           ws += 128 * 512 * 4;
    float* psum            = (float*)ws;           ws += 128 * 512 * 4;
    float* pctx            = (float*)ws;           ws += (size_t)32 * 8 * 4096 * 4;
    unsigned short* Mt     = (unsigned short*)ws;  ws += (size_t)512 * 512 * 2;

    float* attn_out   = (float*)d_out;
    float* scores_out = (float*)d_out + (size_t)NT * CD;

    prep_k<<<7168, 256, 0, stream>>>((const float4*)input, inp_bf,
                                     Wk, Wq, Wv, bk, bq, bv, Wt, biaskqv);

    kqv_gemm_k<<<dim3(12, 64), 256, 0, stream>>>(inp_bf, Wt, biaskqv,
                                                 kbf, qsm, vbf, pmax, psum);

    ksmctx_k<<<dim3(32, 8), 256, 0, stream>>>(kbf, vbf, pmax, psum, ksm, pctx);

    mtred_k<<<1024, 256, 0, stream>>>(pctx, Wr, Mt);

    scores_attn_k<<<4352, 256, 0, stream>>>(qsm, ksm, Mt, br, attn_out, scores_out);
}